// Round 1
// baseline (190.226 us; speedup 1.0000x reference)
//
#include <hip/hip_runtime.h>
#include <math.h>

constexpr int Bn = 16, Hn = 512, Wn = 512;
constexpr int TILE = 64, HALO = 3;
constexpr int TS = TILE + 2 * HALO;   // 70: target tile with halo 3
constexpr int DS = TILE + 2;          // 66: d-tile with halo 1
constexpr float NTOT = 16.f * 512.f * 512.f;

// acc layout: 0 bce_sum, 1 pred_sum, 2 tgt_sum, 3 inter_sum,
//             4..6 cnt(k=3,5,7), 7..9 sum(bce*mask)(k=3,5,7), 10 detail_sum
#define NACC 11

__global__ __launch_bounds__(256) void crack_main(
    const float* __restrict__ logits, const float* __restrict__ target,
    float* __restrict__ acc)
{
    __shared__ unsigned char s_t[TS][TS];     // binary target tile (halo 3)
    __shared__ unsigned char s_h[TS][TILE];   // packed horizontal or/and bits r=1,2,3
    __shared__ float s_d[DS][DS];             // sigmoid(x) - t, halo 1, OOB = 0
    __shared__ float s_red[4][NACC];

    const int tid = threadIdx.x;
    const int x0 = blockIdx.x * TILE;
    const int y0 = blockIdx.y * TILE;
    const size_t base = (size_t)blockIdx.z * Hn * Wn;

    // ---- phase 1: load binary target tile with halo 3 ----
    for (int idx = tid; idx < TS * TS; idx += 256) {
        int r = idx / TS, c = idx % TS;
        int gy = y0 - HALO + r, gx = x0 - HALO + c;
        unsigned char v = 0;
        if ((unsigned)gy < (unsigned)Hn && (unsigned)gx < (unsigned)Wn)
            v = (unsigned char)target[base + (size_t)gy * Wn + gx];
        s_t[r][c] = v;
    }
    __syncthreads();

    // ---- phase 2a: d = sigmoid(logit) - t, halo 1, zero-padded ----
    for (int idx = tid; idx < DS * DS; idx += 256) {
        int r = idx / DS, c = idx % DS;
        int gy = y0 - 1 + r, gx = x0 - 1 + c;
        float d = 0.f;
        if ((unsigned)gy < (unsigned)Hn && (unsigned)gx < (unsigned)Wn) {
            float x = logits[base + (size_t)gy * Wn + gx];
            float p = 1.f / (1.f + __expf(-x));
            d = p - (float)s_t[r + 2][c + 2];
        }
        s_d[r][c] = d;
    }

    // ---- phase 2b: horizontal window OR/AND (radii 1,2,3), bit-packed ----
    for (int idx = tid; idx < TS * TILE; idx += 256) {
        int r = idx / TILE, cc = idx % TILE;
        int o1 = 0, a1 = 1, o2 = 0, a2 = 1, o3 = 0, a3 = 1;
#pragma unroll
        for (int dx = -3; dx <= 3; ++dx) {
            int gx = x0 + cc + dx;
            if ((unsigned)gx < (unsigned)Wn) {
                int v = s_t[r][cc + HALO + dx];
                o3 |= v; a3 &= v;
                if (dx >= -2 && dx <= 2) { o2 |= v; a2 &= v; }
                if (dx >= -1 && dx <= 1) { o1 |= v; a1 &= v; }
            }
        }
        s_h[r][cc] = (unsigned char)(o1 | (a1 << 1) | (o2 << 2) | (a2 << 3) |
                                     (o3 << 4) | (a3 << 5));
    }
    __syncthreads();

    // ---- phase 3: per-pixel elementwise + vertical combine + laplacian ----
    float a[NACC];
#pragma unroll
    for (int i = 0; i < NACC; ++i) a[i] = 0.f;

    const int px = tid & 63;
    const int ty = tid >> 6;
    for (int py = ty; py < TILE; py += 4) {
        float t = (float)s_t[py + HALO][px + HALO];
        float x = logits[base + (size_t)(y0 + py) * Wn + (x0 + px)];
        float d = s_d[py + 1][px + 1];
        float pred = d + t;  // sigmoid(x) recovered without recompute
        float bce = fmaxf(x, 0.f) - x * t + log1pf(__expf(-fabsf(x)));

        a[0] += bce;
        a[1] += pred;
        a[2] += t;
        a[3] += pred * t;

        int o1 = 0, a1 = 1, o2 = 0, a2 = 1, o3 = 0, a3 = 1;
#pragma unroll
        for (int dy = -3; dy <= 3; ++dy) {
            int gy = y0 + py + dy;
            if ((unsigned)gy < (unsigned)Hn) {
                int h = s_h[py + HALO + dy][px];
                if (dy >= -1 && dy <= 1) { o1 |= (h & 1); a1 &= ((h >> 1) & 1); }
                if (dy >= -2 && dy <= 2) { o2 |= ((h >> 2) & 1); a2 &= ((h >> 3) & 1); }
                o3 |= ((h >> 4) & 1); a3 &= ((h >> 5) & 1);
            }
        }
        if (o1 & (a1 ^ 1)) { a[4] += 1.f; a[7] += bce; }
        if (o2 & (a2 ^ 1)) { a[5] += 1.f; a[8] += bce; }
        if (o3 & (a3 ^ 1)) { a[6] += 1.f; a[9] += bce; }

        float lap = s_d[py][px + 1] + s_d[py + 2][px + 1] +
                    s_d[py + 1][px] + s_d[py + 1][px + 2] -
                    4.f * s_d[py + 1][px + 1];
        a[10] += fabsf(lap);
    }

    // ---- phase 4: block reduction + global atomics ----
#pragma unroll
    for (int i = 0; i < NACC; ++i) {
        float v = a[i];
        for (int off = 32; off; off >>= 1) v += __shfl_xor(v, off);
        a[i] = v;
    }
    const int lane = tid & 63, wv = tid >> 6;
    if (lane == 0)
        for (int i = 0; i < NACC; ++i) s_red[wv][i] = a[i];
    __syncthreads();
    if (tid == 0) {
        for (int i = 0; i < NACC; ++i) {
            float v = s_red[0][i] + s_red[1][i] + s_red[2][i] + s_red[3][i];
            atomicAdd(&acc[i], v);
        }
    }
}

__global__ void crack_final(const float* __restrict__ acc, float* __restrict__ out)
{
    if (threadIdx.x == 0) {
        float bce = acc[0] / NTOT;
        float sp = acc[1], st = acc[2], inter = acc[3];
        float uni = sp + st;
        float dice = 1.f - (2.f * inter + 1.f) / (uni + 1.f);
        float fp = sp - inter, fn = st - inter;
        float tvi = (inter + 1.f) / (inter + 0.6f * fp + 0.4f * fn + 1.f);
        float tversky = powf(fmaxf(1.f - tvi, 0.f), 0.75f);
        float tb = 0.f, ns = 0.f;
        for (int i = 0; i < 3; ++i) {
            float cnt = acc[4 + i], sb = acc[7 + i];
            if (cnt >= 1.f) { tb += sb / fmaxf(cnt, 1.f); ns += 1.f; }
        }
        float boundary = tb / fmaxf(ns, 1.f);
        float detail = acc[10] / NTOT;
        out[0] = bce + dice + 0.5f * tversky + 0.5f * boundary + 0.3f * detail;
    }
}

extern "C" void kernel_launch(void* const* d_in, const int* in_sizes, int n_in,
                              void* d_out, int out_size, void* d_ws, size_t ws_size,
                              hipStream_t stream) {
    const float* logits = (const float*)d_in[0];
    const float* target = (const float*)d_in[1];
    float* acc = (float*)d_ws;

    hipMemsetAsync(acc, 0, NACC * sizeof(float), stream);
    dim3 grid(Wn / TILE, Hn / TILE, Bn);
    crack_main<<<grid, dim3(256), 0, stream>>>(logits, target, acc);
    crack_final<<<1, 64, 0, stream>>>(acc, (float*)d_out);
}

// Round 2
// 61.863 us; speedup vs baseline: 3.0750x; 3.0750x over previous
//
#include <hip/hip_runtime.h>
#include <math.h>
#include <stdint.h>

constexpr int Bn = 16, Hn = 512, Wn = 512;
constexpr int Hs = 16;              // strip height per wave
constexpr int GX = Wn / 64;         // 8 column tiles
constexpr int GY = Hn / (4 * Hs);   // 8 groups of 4 strips (4 waves/block)
constexpr int NBLK = GX * GY * Bn;  // 1024 blocks
#define NACC 11
constexpr float NTOT = 16.f * 512.f * 512.f;

// acc: 0 bce, 1 pred, 2 tgt, 3 inter, 4..6 cnt(3,5,7), 7..9 bce*mask(3,5,7), 10 detail

__global__ __launch_bounds__(256) void crack_main(
    const float* __restrict__ logits, const float* __restrict__ target,
    float* __restrict__ partials)
{
    const int tid = threadIdx.x;
    const int lane = tid & 63;
    const int wid = tid >> 6;
    const int x0 = blockIdx.x * 64;
    const int y0 = (blockIdx.y * 4 + wid) * Hs;
    const size_t base = (size_t)blockIdx.z * (size_t)(Hn * Wn);
    const bool leftEdge = (x0 == 0);
    const bool rightEdge = (x0 + 64 >= Wn);

    // sliding windows of horizontally-combined row words (wave-uniform -> SALU/SGPR)
    uint64_t o1[3], a1[3], o2[5], a2[5], o3[7], a3[7];
#pragma unroll
    for (int i = 0; i < 3; ++i) { o1[i] = 0ull; a1[i] = ~0ull; }
#pragma unroll
    for (int i = 0; i < 5; ++i) { o2[i] = 0ull; a2[i] = ~0ull; }
#pragma unroll
    for (int i = 0; i < 7; ++i) { o3[i] = 0ull; a3[i] = ~0ull; }

    float dring[3]  = {0.f, 0.f, 0.f};   // d = sigmoid(x)-t, rows gy-2..gy
    float hlring[3] = {0.f, 0.f, 0.f};   // d at column x0-1 (lane 0 only meaningful)
    float hrring[3] = {0.f, 0.f, 0.f};   // d at column x0+64 (lane 63 only)
    float bring[4]  = {0.f, 0.f, 0.f, 0.f}; // bce rows gy-3..gy
    float acc[NACC];
#pragma unroll
    for (int i = 0; i < NACC; ++i) acc[i] = 0.f;

    for (int it = 0; it < Hs + 6; ++it) {
        const int gy = y0 - 3 + it;
        const bool rowvalid = ((unsigned)gy < (unsigned)Hn);

        // ---- target row -> bit masks ----
        float tval = 0.f, tl = 0.f, tr = 0.f;
        if (rowvalid) {
            const float* trow = target + base + (size_t)gy * Wn;
            tval = trow[x0 + lane];
            if (lane < 3) {
                if (!leftEdge)  tl = trow[x0 - 3 + lane];
                if (!rightEdge) tr = trow[x0 + 64 + lane];
            }
        }
        const uint64_t M  = __ballot(tval > 0.5f);
        const uint64_t bl = __ballot(tl > 0.5f) & 7ull;   // bits 0..2 = cols x0-3..x0-1
        const uint64_t br = __ballot(tr > 0.5f) & 7ull;   // bits 0..2 = cols x0+64..x0+66
        const uint64_t Lo = bl << 61;
        const uint64_t Ro = br;
        const uint64_t La = leftEdge ? (7ull << 61) : Lo; // OOB cols are AND-identity
        const uint64_t Ra = rightEdge ? 7ull : Ro;

        uint64_t no1, na1, no2, na2, no3, na3;
        if (rowvalid) {
            no1 = M   | (M >> 1) | (Ro << 63) | (M << 1) | (Lo >> 63);
            no2 = no1 | (M >> 2) | (Ro << 62) | (M << 2) | (Lo >> 62);
            no3 = no2 | (M >> 3) | (Ro << 61) | (M << 3) | (Lo >> 61);
            na1 = M   & ((M >> 1) | (Ra << 63)) & ((M << 1) | (La >> 63));
            na2 = na1 & ((M >> 2) | (Ra << 62)) & ((M << 2) | (La >> 62));
            na3 = na2 & ((M >> 3) | (Ra << 61)) & ((M << 3) | (La >> 61));
        } else {
            no1 = no2 = no3 = 0ull;      // OOB row: OR-identity
            na1 = na2 = na3 = ~0ull;     // OOB row: AND-identity
        }
        // push windows (static shifts -> register renaming)
        o1[0]=o1[1]; o1[1]=o1[2]; o1[2]=no1;
        a1[0]=a1[1]; a1[1]=a1[2]; a1[2]=na1;
#pragma unroll
        for (int i = 0; i < 4; ++i) { o2[i]=o2[i+1]; a2[i]=a2[i+1]; }
        o2[4]=no2; a2[4]=na2;
#pragma unroll
        for (int i = 0; i < 6; ++i) { o3[i]=o3[i+1]; a3[i]=a3[i+1]; }
        o3[6]=no3; a3[6]=na3;

        // ---- logits row: sigmoid, d, bce, elementwise sums ----
        float d_new = 0.f, hl_new = 0.f, hr_new = 0.f, bce_new = 0.f;
        const bool lrow  = rowvalid && (gy >= y0 - 1) && (gy <= y0 + Hs);
        const bool owned = (gy >= y0) && (gy < y0 + Hs);
        if (lrow) {
            const float* xrow = logits + base + (size_t)gy * Wn;
            const float x = xrow[x0 + lane];
            const float z = __expf(-fabsf(x));
            const float r = __builtin_amdgcn_rcpf(1.f + z);
            const float p = (x >= 0.f) ? r : 1.f - r;
            d_new = p - tval;
            if (owned) {
                bce_new = fmaxf(x, 0.f) - x * tval + __logf(1.f + z);
                acc[0] += bce_new; acc[1] += p; acc[2] += tval; acc[3] += p * tval;
            }
            if (lane == 0 && !leftEdge) {
                const float xl = xrow[x0 - 1];
                const float zl = __expf(-fabsf(xl));
                const float rl = __builtin_amdgcn_rcpf(1.f + zl);
                hl_new = ((xl >= 0.f) ? rl : 1.f - rl) - (float)((Lo >> 63) & 1ull);
            }
            if (lane == 63 && !rightEdge) {
                const float xr = xrow[x0 + 64];
                const float zr = __expf(-fabsf(xr));
                const float rr = __builtin_amdgcn_rcpf(1.f + zr);
                hr_new = ((xr >= 0.f) ? rr : 1.f - rr) - (float)(Ro & 1ull);
            }
        }
        dring[0]=dring[1]; dring[1]=dring[2]; dring[2]=d_new;
        hlring[0]=hlring[1]; hlring[1]=hlring[2]; hlring[2]=hl_new;
        hrring[0]=hrring[1]; hrring[1]=hrring[2]; hrring[2]=hr_new;
        bring[0]=bring[1]; bring[1]=bring[2]; bring[2]=bring[3]; bring[3]=bce_new;

        // ---- outputs at staggered delays (r=1 at gy-1, r=2 at gy-2, r=3 at gy-3) ----
        const int y1 = gy - 1, y2 = gy - 2, y3 = gy - 3;
        if (y1 >= y0 && y1 < y0 + Hs) {
            const uint64_t b1 = (o1[0] | o1[1] | o1[2]) & ~(a1[0] & a1[1] & a1[2]);
            const float f = (float)((b1 >> lane) & 1ull);
            acc[4] += f; acc[7] += f * bring[2];
            // Laplacian at row y1 (d ring holds rows gy-2..gy)
            const float dc = dring[1];
            float dl = __shfl_up(dc, 1);   if (lane == 0)  dl = hlring[1];
            float dr = __shfl_down(dc, 1); if (lane == 63) dr = hrring[1];
            acc[10] += fabsf(dring[0] + dring[2] + dl + dr - 4.f * dc);
        }
        if (y2 >= y0 && y2 < y0 + Hs) {
            const uint64_t b2 = (o2[0]|o2[1]|o2[2]|o2[3]|o2[4]) &
                               ~(a2[0]&a2[1]&a2[2]&a2[3]&a2[4]);
            const float f = (float)((b2 >> lane) & 1ull);
            acc[5] += f; acc[8] += f * bring[1];
        }
        if (y3 >= y0) {  // y3 < y0+Hs always
            const uint64_t b3 = (o3[0]|o3[1]|o3[2]|o3[3]|o3[4]|o3[5]|o3[6]) &
                               ~(a3[0]&a3[1]&a3[2]&a3[3]&a3[4]&a3[5]&a3[6]);
            const float f = (float)((b3 >> lane) & 1ull);
            acc[6] += f; acc[9] += f * bring[0];
        }
    }

    // ---- block reduction: wave shuffle + LDS across 4 waves ----
#pragma unroll
    for (int i = 0; i < NACC; ++i) {
        float v = acc[i];
#pragma unroll
        for (int off = 32; off; off >>= 1) v += __shfl_xor(v, off);
        acc[i] = v;
    }
    __shared__ float s_red[4][NACC];
    if (lane == 0) {
#pragma unroll
        for (int i = 0; i < NACC; ++i) s_red[wid][i] = acc[i];
    }
    __syncthreads();
    if (tid < NACC) {
        const int bid = (blockIdx.z * GY + blockIdx.y) * GX + blockIdx.x;
        partials[(size_t)bid * NACC + tid] =
            s_red[0][tid] + s_red[1][tid] + s_red[2][tid] + s_red[3][tid];
    }
}

__global__ __launch_bounds__(256) void crack_final(
    const float* __restrict__ partials, float* __restrict__ out)
{
    const int tid = threadIdx.x;
    float a[NACC];
#pragma unroll
    for (int i = 0; i < NACC; ++i) a[i] = 0.f;
    for (int b = tid; b < NBLK; b += 256) {
        const float* p = partials + (size_t)b * NACC;
#pragma unroll
        for (int i = 0; i < NACC; ++i) a[i] += p[i];
    }
#pragma unroll
    for (int i = 0; i < NACC; ++i) {
        float v = a[i];
#pragma unroll
        for (int off = 32; off; off >>= 1) v += __shfl_xor(v, off);
        a[i] = v;
    }
    __shared__ float s_red[4][NACC];
    const int lane = tid & 63, wid = tid >> 6;
    if (lane == 0) {
#pragma unroll
        for (int i = 0; i < NACC; ++i) s_red[wid][i] = a[i];
    }
    __syncthreads();
    if (tid == 0) {
        float t[NACC];
        for (int i = 0; i < NACC; ++i)
            t[i] = s_red[0][i] + s_red[1][i] + s_red[2][i] + s_red[3][i];
        const float bce = t[0] / NTOT;
        const float sp = t[1], st = t[2], inter = t[3];
        const float dice = 1.f - (2.f * inter + 1.f) / (sp + st + 1.f);
        const float fp = sp - inter, fn = st - inter;
        const float tvi = (inter + 1.f) / (inter + 0.6f * fp + 0.4f * fn + 1.f);
        const float tversky = powf(fmaxf(1.f - tvi, 0.f), 0.75f);
        float tb = 0.f, ns = 0.f;
        for (int i = 0; i < 3; ++i) {
            const float cnt = t[4 + i], sb = t[7 + i];
            if (cnt >= 1.f) { tb += sb / cnt; ns += 1.f; }
        }
        const float boundary = (ns > 0.f) ? tb / ns : 0.f;
        const float detail = t[10] / NTOT;
        out[0] = bce + dice + 0.5f * tversky + 0.5f * boundary + 0.3f * detail;
    }
}

extern "C" void kernel_launch(void* const* d_in, const int* in_sizes, int n_in,
                              void* d_out, int out_size, void* d_ws, size_t ws_size,
                              hipStream_t stream) {
    const float* logits = (const float*)d_in[0];
    const float* target = (const float*)d_in[1];
    float* partials = (float*)d_ws;   // NBLK * NACC floats = 45 KiB

    dim3 grid(GX, GY, Bn);
    crack_main<<<grid, dim3(256), 0, stream>>>(logits, target, partials);
    crack_final<<<1, 256, 0, stream>>>(partials, (float*)d_out);
}

// Round 3
// 28.377 us; speedup vs baseline: 6.7036x; 2.1801x over previous
//
#include <hip/hip_runtime.h>
#include <math.h>
#include <stdint.h>

constexpr int Hn = 512, Wn = 512, Bn = 16;
constexpr int GX = 2;               // 256-col tiles (4 px/lane)
constexpr int GY = 32;              // 16-row groups (4 waves x 4 rows)
constexpr int NBLK = GX * GY * Bn;  // 1024 blocks
#define NACC 11
constexpr float NTOT = 16.f * 512.f * 512.f;

// partials: 0 bce, 1 sum_d, 2 cnt_t, 3 sum_dt, 4..6 cnt(3,5,7), 7..9 bce*mask(3,5,7), 10 detail

__device__ __forceinline__ float sigm(float x) {
    const float z = __expf(-fabsf(x));
    const float r = __builtin_amdgcn_rcpf(1.f + z);
    return (x >= 0.f) ? r : 1.f - r;
}

__global__ __launch_bounds__(256) void crack_main(
    const float* __restrict__ logits, const float* __restrict__ target,
    float* __restrict__ partials)
{
    const int tid  = threadIdx.x;
    const int lane = tid & 63;
    const int wid  = __builtin_amdgcn_readfirstlane(tid >> 6);
    const int x0 = blockIdx.x * 256;
    const int y0 = blockIdx.y * 16 + wid * 4;     // wave owns rows y0..y0+3
    const int cx = x0 + 4 * lane;                 // my 4 columns cx..cx+3
    const size_t base = (size_t)blockIdx.z * (size_t)(Hn * Wn);
    const bool leftE  = (x0 == 0);
    const bool rightE = (x0 + 256 >= Wn);

    // erosion-complement validity: OOB columns must be 0 in the complement word
    uint32_t validm = 0xFFFu;
    if (leftE  && lane == 0)  validm = 0xFF0u;
    if (rightE && lane == 63) validm = 0x0FFu;

    // ---- per-strip edge target bits (rows y0-3+q, q=0..9), lanes 0..9 / 32..41 ----
    uint32_t elb = 0u, erb = 0u;
    {
        const int gy = y0 - 3 + lane;
        if (lane < 10 && !leftE && (unsigned)gy < (unsigned)Hn) {
            const float4 v = *(const float4*)(target + base + (size_t)gy * Wn + (x0 - 4));
            elb = (uint32_t)v.x | ((uint32_t)v.y << 1) | ((uint32_t)v.z << 2) | ((uint32_t)v.w << 3);
        }
        const int q2 = lane - 32;
        const int gy2 = y0 - 3 + q2;
        if (q2 >= 0 && q2 < 10 && !rightE && (unsigned)gy2 < (unsigned)Hn) {
            const float4 v = *(const float4*)(target + base + (size_t)gy2 * Wn + (x0 + 256));
            erb = (uint32_t)v.x | ((uint32_t)v.y << 1) | ((uint32_t)v.z << 2) | ((uint32_t)v.w << 3);
        }
    }
    // row-aligned edge bits for the d-edge columns (rows y0-1+lane / y0-1+(lane-32))
    const uint32_t elbS = __shfl(elb, lane + 2);
    const uint32_t erbS = __shfl(erb, lane + 2);

    // ---- target rows -> packed horizontal morphology (10 rows) ----
    uint32_t tb[10], po[10], pu[10];
#pragma unroll
    for (int r = 0; r < 10; ++r) {
        const int gy = y0 - 3 + r;
        const bool rowv = ((unsigned)gy < (unsigned)Hn);
        uint32_t m = 0u;
        if (rowv) {
            const float4 v = *(const float4*)(target + base + (size_t)gy * Wn + cx);
            m = (uint32_t)v.x | ((uint32_t)v.y << 1) | ((uint32_t)v.z << 2) | ((uint32_t)v.w << 3);
        }
        tb[r] = m;
        uint32_t ml = __shfl_up(m, 1);
        uint32_t mr = __shfl_down(m, 1);
        const uint32_t el = __shfl(elb, r);
        const uint32_t er = __shfl(erb, 32 + r);
        if (lane == 0)  ml = el;
        if (lane == 63) mr = er;
        // 12-bit window: bit b = column cx-4+b
        const uint32_t w  = ml | (m << 4) | (mr << 8);
        const uint32_t w1 = w  | (w  << 1) | (w  >> 1);
        const uint32_t w2 = w1 | (w1 << 1) | (w1 >> 1);
        const uint32_t w3 = w2 | (w2 << 1) | (w2 >> 1);
        uint32_t wc = (~w) & validm;
        if (!rowv) wc = 0u;                 // OOB row: AND-identity
        const uint32_t u1 = wc | (wc << 1) | (wc >> 1);
        const uint32_t u2 = u1 | (u1 << 1) | (u1 >> 1);
        const uint32_t u3 = u2 | (u2 << 1) | (u2 >> 1);
        po[r] = ((w1 >> 4) & 0xFu) | (((w2 >> 4) & 0xFu) << 4) | (((w3 >> 4) & 0xFu) << 8);
        pu[r] = ((u1 >> 4) & 0xFu) | (((u2 >> 4) & 0xFu) << 4) | (((u3 >> 4) & 0xFu) << 8);
    }

    // ---- edge-column d values (col x0-1 / x0+256), rows y0-1..y0+4 ----
    float dl = 0.f, dr = 0.f;
    {
        const int gy = y0 - 1 + lane;
        if (lane < 6 && !leftE && (unsigned)gy < (unsigned)Hn) {
            const float4 v = *(const float4*)(logits + base + (size_t)gy * Wn + (x0 - 4));
            dl = sigm(v.w) - (float)((elbS >> 3) & 1u);
        }
        const int gy2 = y0 - 1 + (lane - 32);
        if (lane >= 32 && lane < 38 && !rightE && (unsigned)gy2 < (unsigned)Hn) {
            const float4 v = *(const float4*)(logits + base + (size_t)gy2 * Wn + (x0 + 256));
            dr = sigm(v.x) - (float)(erbS & 1u);
        }
    }

    // ---- logits rows: d (6 rows), bce + boundary sums (4 own rows) ----
    float da[6][4];
    float s_bce = 0.f, s_d = 0.f, s_dt = 0.f, s_det = 0.f;
    float s_b1 = 0.f, s_b2 = 0.f, s_b3 = 0.f;
    int c_t = 0, c_1 = 0, c_2 = 0, c_3 = 0;

#pragma unroll
    for (int rr = 0; rr < 6; ++rr) {
        const int gy = y0 - 1 + rr;
        const bool rowv = ((unsigned)gy < (unsigned)Hn);
        float x[4] = {0.f, 0.f, 0.f, 0.f};
        if (rowv) {
            const float4 v = *(const float4*)(logits + base + (size_t)gy * Wn + cx);
            x[0] = v.x; x[1] = v.y; x[2] = v.z; x[3] = v.w;
        }
        const uint32_t m = tb[rr + 2];
        const bool own = (rr >= 1 && rr <= 4);

        uint32_t b = 0u;
        if (own) {
            const int pr = rr + 2;  // = (k=rr-1) + 3
            const uint32_t s3 = po[pr-1] | po[pr] | po[pr+1];
            const uint32_t s5 = s3 | po[pr-2] | po[pr+2];
            const uint32_t s7 = s5 | po[pr-3] | po[pr+3];
            const uint32_t vo = (s3 & 0xFu) | (s5 & 0xF0u) | (s7 & 0xF00u);
            const uint32_t q3 = pu[pr-1] | pu[pr] | pu[pr+1];
            const uint32_t q5 = q3 | pu[pr-2] | pu[pr+2];
            const uint32_t q7 = q5 | pu[pr-3] | pu[pr+3];
            const uint32_t vu = (q3 & 0xFu) | (q5 & 0xF0u) | (q7 & 0xF00u);
            b = vo & vu;
            c_1 += __popc(b & 0xFu);
            c_2 += __popc(b & 0xF0u);
            c_3 += __popc(b & 0xF00u);
            c_t += __popc(m & 0xFu);
        }
#pragma unroll
        for (int j = 0; j < 4; ++j) {
            const float z  = __expf(-fabsf(x[j]));
            const float r1 = __builtin_amdgcn_rcpf(1.f + z);
            const float p  = (x[j] >= 0.f) ? r1 : 1.f - r1;
            const float tf = (float)((m >> j) & 1u);
            const float d  = rowv ? (p - tf) : 0.f;
            da[rr][j] = d;
            if (own) {
                const float s   = (1.f - 2.f * tf) * x[j];
                const float bce = fmaxf(s, 0.f) + __logf(1.f + z);
                s_bce += bce; s_d += d; s_dt += d * tf;
                s_b1 += (float)((b >> j) & 1u) * bce;
                s_b2 += (float)((b >> (4 + j)) & 1u) * bce;
                s_b3 += (float)((b >> (8 + j)) & 1u) * bce;
            }
        }
    }

    // ---- Laplacian (4 own rows) ----
#pragma unroll
    for (int k = 0; k < 4; ++k) {
        const float cw = da[k+1][3], c0 = da[k+1][0];
        float sl = __shfl_up(cw, 1);
        float sr = __shfl_down(c0, 1);
        const float el = __shfl(dl, k + 1);
        const float er = __shfl(dr, 32 + k + 1);
        if (lane == 0)  sl = el;
        if (lane == 63) sr = er;
        const float h0 = sl          + da[k+1][1];
        const float h1 = da[k+1][0] + da[k+1][2];
        const float h2 = da[k+1][1] + da[k+1][3];
        const float h3 = da[k+1][2] + sr;
        s_det += fabsf(h0 + da[k][0] + da[k+2][0] - 4.f * da[k+1][0]);
        s_det += fabsf(h1 + da[k][1] + da[k+2][1] - 4.f * da[k+1][1]);
        s_det += fabsf(h2 + da[k][2] + da[k+2][2] - 4.f * da[k+1][2]);
        s_det += fabsf(h3 + da[k][3] + da[k+2][3] - 4.f * da[k+1][3]);
    }

    // ---- block reduction ----
    float acc[NACC];
    acc[0] = s_bce; acc[1] = s_d; acc[2] = (float)c_t; acc[3] = s_dt;
    acc[4] = (float)c_1; acc[5] = (float)c_2; acc[6] = (float)c_3;
    acc[7] = s_b1; acc[8] = s_b2; acc[9] = s_b3; acc[10] = s_det;
#pragma unroll
    for (int i = 0; i < NACC; ++i) {
        float v = acc[i];
#pragma unroll
        for (int off = 32; off; off >>= 1) v += __shfl_xor(v, off);
        acc[i] = v;
    }
    __shared__ float s_red[4][NACC];
    if (lane == 0) {
#pragma unroll
        for (int i = 0; i < NACC; ++i) s_red[wid][i] = acc[i];
    }
    __syncthreads();
    if (tid < NACC) {
        const int bid = (blockIdx.z * GY + blockIdx.y) * GX + blockIdx.x;
        partials[(size_t)bid * NACC + tid] =
            s_red[0][tid] + s_red[1][tid] + s_red[2][tid] + s_red[3][tid];
    }
}

__global__ __launch_bounds__(256) void crack_final(
    const float* __restrict__ partials, float* __restrict__ out)
{
    const int tid = threadIdx.x;
    float a[NACC];
#pragma unroll
    for (int i = 0; i < NACC; ++i) a[i] = 0.f;
    for (int b = tid; b < NBLK; b += 256) {
        const float* p = partials + (size_t)b * NACC;
#pragma unroll
        for (int i = 0; i < NACC; ++i) a[i] += p[i];
    }
#pragma unroll
    for (int i = 0; i < NACC; ++i) {
        float v = a[i];
#pragma unroll
        for (int off = 32; off; off >>= 1) v += __shfl_xor(v, off);
        a[i] = v;
    }
    __shared__ float s_red[4][NACC];
    const int lane = tid & 63, wid = tid >> 6;
    if (lane == 0) {
#pragma unroll
        for (int i = 0; i < NACC; ++i) s_red[wid][i] = a[i];
    }
    __syncthreads();
    if (tid == 0) {
        float t[NACC];
        for (int i = 0; i < NACC; ++i)
            t[i] = s_red[0][i] + s_red[1][i] + s_red[2][i] + s_red[3][i];
        const float bce   = t[0] / NTOT;
        const float st    = t[2];
        const float sp    = t[1] + t[2];
        const float inter = t[3] + t[2];
        const float dice = 1.f - (2.f * inter + 1.f) / (sp + st + 1.f);
        const float fp = sp - inter, fn = st - inter;
        const float tvi = (inter + 1.f) / (inter + 0.6f * fp + 0.4f * fn + 1.f);
        const float tversky = powf(fmaxf(1.f - tvi, 0.f), 0.75f);
        float tb = 0.f, ns = 0.f;
        for (int i = 0; i < 3; ++i) {
            const float cnt = t[4 + i], sb = t[7 + i];
            if (cnt >= 1.f) { tb += sb / cnt; ns += 1.f; }
        }
        const float boundary = (ns > 0.f) ? tb / ns : 0.f;
        const float detail = t[10] / NTOT;
        out[0] = bce + dice + 0.5f * tversky + 0.5f * boundary + 0.3f * detail;
    }
}

extern "C" void kernel_launch(void* const* d_in, const int* in_sizes, int n_in,
                              void* d_out, int out_size, void* d_ws, size_t ws_size,
                              hipStream_t stream) {
    const float* logits = (const float*)d_in[0];
    const float* target = (const float*)d_in[1];
    float* partials = (float*)d_ws;   // NBLK * NACC floats = 45 KiB

    dim3 grid(GX, GY, Bn);
    crack_main<<<grid, dim3(256), 0, stream>>>(logits, target, partials);
    crack_final<<<1, 256, 0, stream>>>(partials, (float*)d_out);
}